// Round 14
// baseline (110.469 us; speedup 1.0000x reference)
//
#include <hip/hip_runtime.h>
#include <math.h>

// NoisyTopKRouter, round 14: canonical MFMA GEMM at 3 blocks/CU.
// BM=32, 256 thr (4 waves), grid T/32=512, LDS 42.5KB -> 3 blocks/CU.
// B staged via global_load_lds width=16 (linear, conflict-free reads);
// A reg-staged f32->f16 into padded LDS. 1-pass f16-hi + top-3 gap
// certificate + gathered 3-limb exact fixup (unchanged).

typedef _Float16 f16;
typedef _Float16 f16x8 __attribute__((ext_vector_type(8)));
typedef float    f32x4 __attribute__((ext_vector_type(4)));

#define NEMBD 2048
#define NEXP  64
#define BM    32              // fused kernel tokens/block
#define ASTR  72              // A LDS row stride (f16)
#define LSTR  36              // LG col stride (f32)
#define WSCALE 64.0f
#define INV_WSCALE 0.015625f
#define TAU_C 2.2e-3f

union F4H8 { float4 f; f16x8 h; };

__device__ __forceinline__ f16x8 ld16h(const f16* p) {
    F4H8 u; u.f = *(const float4*)p; return u.h;
}

__device__ __forceinline__ void glds16(const void* g, void* l) {
    __builtin_amdgcn_global_load_lds(
        (const __attribute__((address_space(1))) void*)g,
        (__attribute__((address_space(3))) void*)l, 16, 0, 0);
}

// ---------- kernel 0: W -> x64-scaled f16 limbs, [chunk][kgrp][col][8] ----------
__global__ __launch_bounds__(256) void build_wt(
    const float* __restrict__ Wr, const float* __restrict__ Wn,
    f16* __restrict__ wt_hi, f16* __restrict__ wt_lo,
    int* __restrict__ cnt)
{
    if (blockIdx.x == 0 && threadIdx.x == 0) *cnt = 0;

    __shared__ float ws[32][129];
    const int c = blockIdx.x, t = threadIdx.x;
    const int k0 = c * 32;
    {
        const int k  = t >> 3;
        const int n8 = (t & 7) << 3;
        const float* s0 = Wr + (size_t)(k0 + k) * NEXP + n8;
        const float* s1 = Wn + (size_t)(k0 + k) * NEXP + n8;
        #pragma unroll
        for (int j = 0; j < 8; ++j) ws[k][n8 + j] = s0[j];
        #pragma unroll
        for (int j = 0; j < 8; ++j) ws[k][64 + n8 + j] = s1[j];
    }
    __syncthreads();
    {
        const int n  = t >> 1;           // col 0..127
        const int kh = (t & 1) << 4;     // k base 0 or 16
        const int kg = kh >> 3;          // kgrp 0 or 2
        f16x8 hv0, hv1, lv0, lv1;
        #pragma unroll
        for (int j = 0; j < 8; ++j) {
            const float v = ws[kh + j][n] * WSCALE;
            const f16 h = (f16)v;
            hv0[j] = h; lv0[j] = (f16)(v - (float)h);
        }
        #pragma unroll
        for (int j = 0; j < 8; ++j) {
            const float v = ws[kh + 8 + j][n] * WSCALE;
            const f16 h = (f16)v;
            hv1[j] = h; lv1[j] = (f16)(v - (float)h);
        }
        const size_t b0 = (size_t)c * 4096 + (size_t)kg * 1024 + n * 8;
        *(f16x8*)(wt_hi + b0)        = hv0;
        *(f16x8*)(wt_hi + b0 + 1024) = hv1;
        *(f16x8*)(wt_lo + b0)        = lv0;
        *(f16x8*)(wt_lo + b0 + 1024) = lv1;
    }
}

// ---------- kernel 1: fused router, 3 blocks/CU ----------
// 256 thr = 4 waves; wave w: rows (w&1)*16, cols (w>>1)*64 (4 col-frags).
__global__ __launch_bounds__(256, 3) void router_fused10(
    const float* __restrict__ x, const float* __restrict__ eps,
    const f16* __restrict__ wt_hi,
    const float* __restrict__ br, const float* __restrict__ bn,
    float* __restrict__ out_r, float* __restrict__ out_idx,
    int* __restrict__ cnt, int* __restrict__ list)
{
    // XH [2][32][72] f16 @0 (9216B); WB [2][16384B] @9216; TK @41984
    __shared__ __align__(16) char SH[42496];
    f16*  XH = (f16*)SH;
    char* WB = SH + 9216;
    float* LG = (float*)SH;          // [128][36] f32 overlay (epilogue)
    float* TK = (float*)(SH + 41984);

    const int tid  = threadIdx.x;
    const int lane = tid & 63;
    const int w    = tid >> 6;
    const int wr   = w & 1;
    const int wc   = w >> 1;
    const int m0   = blockIdx.x * BM;

    const int row16 = lane & 15;
    const int kgrp  = lane >> 4;

    // A stage map: row = tid>>3 (0..31), k off = (tid&7)*8 floats
    const int srow = tid >> 3;
    const int skof = (tid & 7) << 3;
    const float* axsrc = x + (size_t)(m0 + srow) * NEMBD + skof;
    const int axoff = srow * ASTR + skof;     // f16 units

    // fragment offsets
    const int aof  = (wr * 16 + row16) * ASTR + kgrp * 8;   // f16 units
    const int bofb = kgrp * 2048 + (wc * 64 + row16) * 16;  // bytes (cf adds 256)

    f32x4 acc[4];
    #pragma unroll
    for (int cf = 0; cf < 4; ++cf) acc[cf] = (f32x4){0.f, 0.f, 0.f, 0.f};

#define CVT8(A0, A1, hv) do { \
    hv[0] = (f16)A0.x; hv[1] = (f16)A0.y; hv[2] = (f16)A0.z; hv[3] = (f16)A0.w; \
    hv[4] = (f16)A1.x; hv[5] = (f16)A1.y; hv[6] = (f16)A1.z; hv[7] = (f16)A1.w; } while (0)

#define STAGE_B(s, dstbuf) do { \
    const size_t sb = (size_t)(s) * 8192; \
    char* db = WB + (dstbuf) * 16384; \
    _Pragma("unroll") \
    for (int j = 0; j < 4; ++j) { \
        const int co = (w * 4 + j) * 512; \
        glds16(wt_hi + sb + co + lane * 8, db + co * 2); \
    } } while (0)

    // ---- prologue: stage step 0 into buf 0 ----
    {
        STAGE_B(0, 0);
        const float4 a0 = *(const float4*)(axsrc);
        const float4 a1 = *(const float4*)(axsrc + 4);
        f16x8 hv; CVT8(a0, a1, hv);
        *(f16x8*)(XH + axoff) = hv;
        __syncthreads();
    }

    // ---- main loop: 32 K-steps of 64 ----
    for (int s = 0; s < 32; ++s) {
        const int buf = s & 1;
        const f16*  XA  = XH + buf * 2304;
        const char* WBb = WB + buf * 16384;
        const bool st = (s + 1) < 32;
        float4 a0_, a1_;
        if (st) {
            STAGE_B(s + 1, buf ^ 1);
            a0_ = *(const float4*)(axsrc + (size_t)(s + 1) * 64);
            a1_ = *(const float4*)(axsrc + (size_t)(s + 1) * 64 + 4);
        }
        #pragma unroll
        for (int ks = 0; ks < 2; ++ks) {
            const f16x8 ah = *(const f16x8*)(XA + aof + ks * 32);
            #pragma unroll
            for (int cf = 0; cf < 4; ++cf) {
                const f16x8 bh = *(const f16x8*)(WBb + ks * 8192 + bofb + cf * 256);
                acc[cf] = __builtin_amdgcn_mfma_f32_16x16x32_f16(ah, bh, acc[cf], 0, 0, 0);
            }
        }
        if (st) {
            f16x8 hv; CVT8(a0_, a1_, hv);
            *(f16x8*)(XH + (buf ^ 1) * 2304 + axoff) = hv;
        }
        __syncthreads();
    }
#undef STAGE_B
#undef CVT8

    // ---- epilogue: descale + bias -> LG overlay ----
    {
        const int tokb = wr * 16 + kgrp * 4;
        #pragma unroll
        for (int cf = 0; cf < 4; ++cf) {
            const int col = wc * 64 + cf * 16 + row16;
            const float bias = (col < NEXP) ? br[col] : bn[col - NEXP];
            #pragma unroll
            for (int r = 0; r < 4; ++r)
                LG[col * LSTR + tokb + r] = acc[cf][r] * INV_WSCALE + bias;
        }
    }
    __syncthreads();

    // ---- bias + noise + top-3 + certification: 4 lanes per token ----
    if (tid < 128) {
        const int t = tid >> 2;          // token 0..31
        const int q = tid & 3;
        const float* ep = eps + (size_t)(m0 + t) * NEXP;
        float v1 = -1e30f, v2 = -1e30f, v3 = -1e30f;
        int i1 = 0, i2 = 0, i3 = 0;
        float mx = 0.f;
        for (int j = 0; j < 16; ++j) {
            const int e = q * 16 + j;
            const float r  = LG[e * LSTR + t];
            const float nr = LG[(NEXP + e) * LSTR + t];
            const float sp = fmaxf(nr, 0.f) + log1pf(expf(-fabsf(nr)));
            const float ev = ep[e];
            mx = fmaxf(mx, fabsf(ev));
            const float noisy = fmaf(ev, sp, r);
            if (noisy > v1) { v3 = v2; i3 = i2; v2 = v1; i2 = i1; v1 = noisy; i1 = e; }
            else if (noisy > v2) { v3 = v2; i3 = i2; v2 = noisy; i2 = e; }
            else if (noisy > v3) { v3 = noisy; i3 = e; }
        }
        #pragma unroll
        for (int s = 0; s < 2; ++s) {
            const int dist = 1 << s;
            const float ov1 = __shfl_xor(v1, dist);
            const float ov2 = __shfl_xor(v2, dist);
            const float ov3 = __shfl_xor(v3, dist);
            const int   oi1 = __shfl_xor(i1, dist);
            const int   oi2 = __shfl_xor(i2, dist);
            const int   oi3 = __shfl_xor(i3, dist);
            mx = fmaxf(mx, __shfl_xor(mx, dist));
            const int h = (q >> s) & 1;
            float a1, a2, a3, bb1, bb2, bb3; int ai1, ai2, ai3, bj1, bj2, bj3;
            if (h) { a1=ov1;a2=ov2;a3=ov3;ai1=oi1;ai2=oi2;ai3=oi3;
                     bb1=v1;bb2=v2;bb3=v3;bj1=i1;bj2=i2;bj3=i3; }
            else   { a1=v1;a2=v2;a3=v3;ai1=i1;ai2=i2;ai3=i3;
                     bb1=ov1;bb2=ov2;bb3=ov3;bj1=oi1;bj2=oi2;bj3=oi3; }
            #pragma unroll
            for (int bi = 0; bi < 3; ++bi) {
                const float bv = (bi == 0) ? bb1 : (bi == 1) ? bb2 : bb3;
                const int   bj = (bi == 0) ? bj1 : (bi == 1) ? bj2 : bj3;
                if (bv > a1) { a3=a2;ai3=ai2; a2=a1;ai2=ai1; a1=bv;ai1=bj; }
                else if (bv > a2) { a3=a2;ai3=ai2; a2=bv;ai2=bj; }
                else if (bv > a3) { a3=bv;ai3=bj; }
            }
            v1=a1;v2=a2;v3=a3;i1=ai1;i2=ai2;i3=ai3;
        }
        if (q == 0) {
            const float e1 = fabsf(ep[i1]);
            const float e2 = fabsf(ep[i2]);
            const float em = fmaxf(e1, e2);
            const float t12 = TAU_C * sqrtf(2.f + e1 * e1 + e2 * e2);
            const float t23 = TAU_C * sqrtf(2.f + em * em + mx * mx);
            if ((v1 - v2 < t12) || (v2 - v3 < t23)) {
                const int ai = atomicAdd(cnt, 1);
                list[ai] = m0 + t;
            }
            const float ex = expf(v2 - v1);
            const float p1 = 1.f / (1.f + ex);
            TK[0 * BM + t] = p1;
            TK[1 * BM + t] = ex * p1;
            TK[2 * BM + t] = (float)i1;
            TK[3 * BM + t] = (float)i2;
        }
    }
    __syncthreads();

    // ---- write r_out (8 floats/thread) + idx ----
    {
        const int t  = tid >> 3;            // 0..31
        const int c8 = (tid & 7) << 3;
        const float p1 = TK[t], p2 = TK[BM + t];
        const int i1 = (int)TK[2 * BM + t], i2 = (int)TK[3 * BM + t];
        float buf[8];
        #pragma unroll
        for (int jj = 0; jj < 8; ++jj) {
            const int e = c8 + jj;
            buf[jj] = (e == i1) ? p1 : (e == i2) ? p2 : 0.f;
        }
        float* dst = out_r + (size_t)(m0 + t) * NEXP + c8;
        *(float4*)(dst + 0) = *(float4*)(buf + 0);
        *(float4*)(dst + 4) = *(float4*)(buf + 4);
    }
    if (tid < BM) {
        float2 v = make_float2(TK[2 * BM + tid], TK[3 * BM + tid]);
        *(float2*)(out_idx + (size_t)(m0 + tid) * 2) = v;
    }
}

// ---------- kernel 2: gathered mini-GEMM fixup (3-limb exact, unchanged) ----------
__global__ __launch_bounds__(512, 2) void router_fixup2(
    const float* __restrict__ x, const float* __restrict__ eps,
    const f16* __restrict__ wt_hi, const f16* __restrict__ wt_lo,
    const float* __restrict__ br, const float* __restrict__ bn,
    float* __restrict__ out_r, float* __restrict__ out_idx,
    const int* __restrict__ cnt, const int* __restrict__ list)
{
    __shared__ __align__(16) char SH[52480];
    f16* XH = (f16*)SH;                      // [64][72]
    f16* XL = XH + 64 * ASTR;
    f16* WH = (f16*)(SH + 18432);
    f16* WL = WH + 8192;
    float* LG = (float*)SH;                  // [128][68] overlay
    float* TK = (float*)(SH + 51200);
    int*   LT = (int*)(SH + 52224);

    const int n  = cnt[0];
    const int m0 = blockIdx.x * 64;
    if (m0 >= n) return;

    const int tid  = threadIdx.x;
    const int lane = tid & 63;
    const int w    = tid >> 6;
    const int wr   = w & 1;
    const int wc   = w >> 1;

    if (tid < 64) LT[tid] = (m0 + tid < n) ? list[m0 + tid] : -1;
    __syncthreads();

    const int row16 = lane & 15;
    const int kgrp  = lane >> 4;

    const int srow = tid >> 3;
    const int skof = (tid & 7) << 3;
    const int tok_s = (LT[srow] >= 0) ? LT[srow] : LT[0];
    const float* axsrc = x + (size_t)tok_s * NEMBD + skof;
    const int axoff = srow * ASTR + skof;

    const f16* bsrc_h = wt_hi + tid * 16;
    const f16* bsrc_l = wt_lo + tid * 16;

    const int aof0 = (wr * 32 + row16) * ASTR + kgrp * 8;
    const int aof1 = aof0 + 16 * ASTR;
    const int bof0 = kgrp * 1024 + (wc * 32 + row16) * 8;
    const int bof1 = bof0 + 16 * 8;

    f32x4 acc00 = {0.f,0.f,0.f,0.f}, acc01 = {0.f,0.f,0.f,0.f};
    f32x4 acc10 = {0.f,0.f,0.f,0.f}, acc11 = {0.f,0.f,0.f,0.f};

    for (int s = 0; s < 32; ++s) {
        const float4 a0 = *(const float4*)(axsrc + (size_t)s * 64);
        const float4 a1 = *(const float4*)(axsrc + (size_t)s * 64 + 4);
        F4H8 bh0_, bh1_, bl0_, bl1_;
        bh0_.f = *(const float4*)(bsrc_h + (size_t)s * 8192);
        bh1_.f = *(const float4*)(bsrc_h + (size_t)s * 8192 + 8);
        bl0_.f = *(const float4*)(bsrc_l + (size_t)s * 8192);
        bl1_.f = *(const float4*)(bsrc_l + (size_t)s * 8192 + 8);
        f16x8 hv, lv;
        {
            const float av[8] = {a0.x, a0.y, a0.z, a0.w, a1.x, a1.y, a1.z, a1.w};
            #pragma unroll
            for (int j = 0; j < 8; ++j) {
                const f16 h = (f16)av[j];
                hv[j] = h; lv[j] = (f16)(av[j] - (float)h);
            }
        }
        *(f16x8*)(XH + axoff) = hv;
        *(f16x8*)(XL + axoff) = lv;
        *(f16x8*)(WH + tid * 16)     = bh0_.h;
        *(f16x8*)(WH + tid * 16 + 8) = bh1_.h;
        *(f16x8*)(WL + tid * 16)     = bl0_.h;
        *(f16x8*)(WL + tid * 16 + 8) = bl1_.h;
        __syncthreads();
        #pragma unroll
        for (int ks = 0; ks < 2; ++ks) {
            const f16x8 ah0 = *(const f16x8*)(XH + aof0 + ks * 32);
            const f16x8 al0 = *(const f16x8*)(XL + aof0 + ks * 32);
            const f16x8 ah1 = *(const f16x8*)(XH + aof1 + ks * 32);
            const f16x8 al1 = *(const f16x8*)(XL + aof1 + ks * 32);
            const f16x8 bh0 = *(const f16x8*)(WH + ks * 4096 + bof0);
            const f16x8 bh1 = *(const f16x8*)(WH + ks * 4096 + bof1);
            const f16x8 bl0 = *(const f16x8*)(WL + ks * 4096 + bof0);
            const f16x8 bl1 = *(const f16x8*)(WL + ks * 4096 + bof1);
            acc00 = __builtin_amdgcn_mfma_f32_16x16x32_f16(ah0, bh0, acc00, 0, 0, 0);
            acc00 = __builtin_amdgcn_mfma_f32_16x16x32_f16(al0, bh0, acc00, 0, 0, 0);
            acc00 = __builtin_amdgcn_mfma_f32_16x16x32_f16(ah0, bl0, acc00, 0, 0, 0);
            acc01 = __builtin_amdgcn_mfma_f32_16x16x32_f16(ah0, bh1, acc01, 0, 0, 0);
            acc01 = __builtin_amdgcn_mfma_f32_16x16x32_f16(al0, bh1, acc01, 0, 0, 0);
            acc01 = __builtin_amdgcn_mfma_f32_16x16x32_f16(ah0, bl1, acc01, 0, 0, 0);
            acc10 = __builtin_amdgcn_mfma_f32_16x16x32_f16(ah1, bh0, acc10, 0, 0, 0);
            acc10 = __builtin_amdgcn_mfma_f32_16x16x32_f16(al1, bh0, acc10, 0, 0, 0);
            acc10 = __builtin_amdgcn_mfma_f32_16x16x32_f16(ah1, bl0, acc10, 0, 0, 0);
            acc11 = __builtin_amdgcn_mfma_f32_16x16x32_f16(ah1, bh1, acc11, 0, 0, 0);
            acc11 = __builtin_amdgcn_mfma_f32_16x16x32_f16(al1, bh1, acc11, 0, 0, 0);
            acc11 = __builtin_amdgcn_mfma_f32_16x16x32_f16(ah1, bl1, acc11, 0, 0, 0);
        }
        __syncthreads();
    }

    {
        const int tokb = kgrp << 2;
        #pragma unroll
        for (int fj = 0; fj < 4; ++fj) {
            const int i = fj >> 1, j = fj & 1;
            const int col = wc * 32 + j * 16 + row16;
            const int tok = wr * 32 + i * 16 + tokb;
            const float bias = (col < NEXP) ? br[col] : bn[col - NEXP];
            const f32x4 a = (fj == 0) ? acc00 : (fj == 1) ? acc01 : (fj == 2) ? acc10 : acc11;
            #pragma unroll
            for (int r = 0; r < 4; ++r)
                LG[col * 68 + tok + r] = a[r] * INV_WSCALE + bias;
        }
    }
    __syncthreads();

    if (tid < 256) {
        const int t = tid >> 2;
        const int q = tid & 3;
        const int tok = LT[t];
        const float* ep = eps + (size_t)(tok >= 0 ? tok : LT[0]) * NEXP;
        float v1 = -1e30f, v2 = -1e30f;
        int i1 = 0, i2 = 0;
        for (int j = 0; j < 16; ++j) {
            const int e = q * 16 + j;
            const float r  = LG[e * 68 + t];
            const float nr = LG[(NEXP + e) * 68 + t];
            const float sp = fmaxf(nr, 0.f) + log1pf(expf(-fabsf(nr)));
            const float noisy = fmaf(ep[e], sp, r);
            if (noisy > v1) { v2 = v1; i2 = i1; v1 = noisy; i1 = e; }
            else if (noisy > v2) { v2 = noisy; i2 = e; }
        }
        #pragma unroll
        for (int s = 0; s < 2; ++s) {
            const int dist = 1 << s;
            const float ov1 = __shfl_xor(v1, dist);
            const float ov2 = __shfl_xor(v2, dist);
            const int   oi1 = __shfl_xor(i1, dist);
            const int   oi2 = __shfl_xor(i2, dist);
            const int h = (q >> s) & 1;
            float a1, a2, bb1, bb2; int ai1, ai2, bj1, bj2;
            if (h) { a1 = ov1; a2 = ov2; ai1 = oi1; ai2 = oi2; bb1 = v1;  bb2 = v2;  bj1 = i1;  bj2 = i2; }
            else   { a1 = v1;  a2 = v2;  ai1 = i1;  ai2 = i2;  bb1 = ov1; bb2 = ov2; bj1 = oi1; bj2 = oi2; }
            if (bb1 > a1) {
                v1 = bb1; i1 = bj1;
                if (a1 >= bb2) { v2 = a1; i2 = ai1; } else { v2 = bb2; i2 = bj2; }
            } else {
                v1 = a1; i1 = ai1;
                if (bb1 > a2) { v2 = bb1; i2 = bj1; } else { v2 = a2; i2 = ai2; }
            }
        }
        if (q == 0) {
            const float ex = expf(v2 - v1);
            const float p1 = 1.f / (1.f + ex);
            TK[0 * 64 + t] = p1;
            TK[1 * 64 + t] = ex * p1;
            TK[2 * 64 + t] = (float)i1;
            TK[3 * 64 + t] = (float)i2;
        }
    }
    __syncthreads();

    {
        const int t  = tid >> 3;
        const int c8 = (tid & 7) << 3;
        const int tok = LT[t];
        if (tok >= 0) {
            const float p1 = TK[t], p2 = TK[64 + t];
            const int i1 = (int)TK[128 + t], i2 = (int)TK[192 + t];
            float buf[8];
            #pragma unroll
            for (int jj = 0; jj < 8; ++jj) {
                const int e = c8 + jj;
                buf[jj] = (e == i1) ? p1 : (e == i2) ? p2 : 0.f;
            }
            float* dst = out_r + (size_t)tok * NEXP + c8;
            *(float4*)(dst + 0) = *(float4*)(buf + 0);
            *(float4*)(dst + 4) = *(float4*)(buf + 4);
        }
    }
    if (tid < 64 && LT[tid] >= 0) {
        float2 v = make_float2(TK[128 + tid], TK[192 + tid]);
        *(float2*)(out_idx + (size_t)LT[tid] * 2) = v;
    }
}

// ---------- fallback: fused f32 kernel (insurance only) ----------
__global__ __launch_bounds__(256) void router_fused_f32(
    const float* __restrict__ x, const float* __restrict__ eps,
    const float* __restrict__ Wr, const float* __restrict__ br,
    const float* __restrict__ Wn, const float* __restrict__ bn,
    float* __restrict__ out_r, float* __restrict__ out_idx)
{
    __shared__ float xsm[32][64];
    __shared__ float ws2[32][128];
    __shared__ float lg[128][64];
    __shared__ float tk[4][64];
    const int tid = threadIdx.x;
    const int tx = tid & 15, ty = tid >> 4;
    const int m0 = blockIdx.x * 64;
    float acc[4][8];
    #pragma unroll
    for (int i = 0; i < 4; ++i)
        #pragma unroll
        for (int j = 0; j < 8; ++j) acc[i][j] = 0.f;
    for (int kc = 0; kc < NEMBD; kc += 32) {
        {
            const int tm = tid >> 2, kk = (tid & 3) << 3;
            const float* src = x + (size_t)(m0 + tm) * NEMBD + kc + kk;
            const float4 a = *(const float4*)(src);
            const float4 b = *(const float4*)(src + 4);
            xsm[kk+0][tm]=a.x; xsm[kk+1][tm]=a.y; xsm[kk+2][tm]=a.z; xsm[kk+3][tm]=a.w;
            xsm[kk+4][tm]=b.x; xsm[kk+5][tm]=b.y; xsm[kk+6][tm]=b.z; xsm[kk+7][tm]=b.w;
        }
        {
            const int kr = tid >> 3, q = tid & 7;
            const float* src = (q < 4)
                ? (Wr + (size_t)(kc + kr) * NEXP + (q << 4))
                : (Wn + (size_t)(kc + kr) * NEXP + ((q - 4) << 4));
            float* dst = &ws2[kr][q << 4];
            #pragma unroll
            for (int j = 0; j < 16; ++j) dst[j] = src[j];
        }
        __syncthreads();
        #pragma unroll
        for (int k = 0; k < 32; ++k) {
            const float4 xv = *(const float4*)&xsm[k][ty << 2];
            const float4 wa = *(const float4*)&ws2[k][tx << 3];
            const float4 wb = *(const float4*)&ws2[k][(tx << 3) + 4];
            const float xr[4] = {xv.x, xv.y, xv.z, xv.w};
            const float wcx[8] = {wa.x, wa.y, wa.z, wa.w, wb.x, wb.y, wb.z, wb.w};
            #pragma unroll
            for (int i = 0; i < 4; ++i)
                #pragma unroll
                for (int j = 0; j < 8; ++j)
                    acc[i][j] = fmaf(xr[i], wcx[j], acc[i][j]);
        }
        __syncthreads();
    }
    {
        const int n0 = tx << 3;
        #pragma unroll
        for (int j = 0; j < 8; ++j) {
            const int nn = n0 + j;
            const float b = (nn < NEXP) ? br[nn] : bn[nn - NEXP];
            #pragma unroll
            for (int i = 0; i < 4; ++i)
                lg[nn][(ty << 2) + i] = acc[i][j] + b;
        }
    }
    __syncthreads();
    if (tid < 64) {
        const int t = tid;
        const float* ep = eps + (size_t)(m0 + t) * NEXP;
        float v1 = -1e30f, v2 = -1e30f; int i1 = 0, i2 = 0;
        for (int e = 0; e < NEXP; ++e) {
            const float r = lg[e][t], nr = lg[NEXP + e][t];
            const float sp = fmaxf(nr, 0.f) + log1pf(expf(-fabsf(nr)));
            const float noisy = fmaf(ep[e], sp, r);
            if (noisy > v1) { v2=v1; i2=i1; v1=noisy; i1=e; }
            else if (noisy > v2) { v2=noisy; i2=e; }
        }
        const float ex = expf(v2 - v1);
        const float p1 = 1.f / (1.f + ex);
        tk[0][t]=p1; tk[1][t]=ex*p1; tk[2][t]=(float)i1; tk[3][t]=(float)i2;
    }
    __syncthreads();
    {
        const int t = tid >> 2, c = tid & 3;
        const float p1 = tk[0][t], p2 = tk[1][t];
        const int i1 = (int)tk[2][t], i2 = (int)tk[3][t];
        float buf[16];
        #pragma unroll
        for (int j = 0; j < 16; ++j) {
            const int e = (c << 4) + j;
            buf[j] = (e == i1) ? p1 : (e == i2) ? p2 : 0.f;
        }
        float* dst = out_r + (size_t)(m0 + t) * NEXP + (c << 4);
        *(float4*)(dst+0)=*(float4*)(buf+0); *(float4*)(dst+4)=*(float4*)(buf+4);
        *(float4*)(dst+8)=*(float4*)(buf+8); *(float4*)(dst+12)=*(float4*)(buf+12);
    }
    if (tid < 64) {
        float2 v = make_float2(tk[2][tid], tk[3][tid]);
        *(float2*)(out_idx + (size_t)(m0 + tid) * 2) = v;
    }
}

extern "C" void kernel_launch(void* const* d_in, const int* in_sizes, int n_in,
                              void* d_out, int out_size, void* d_ws, size_t ws_size,
                              hipStream_t stream) {
    const float* x  = (const float*)d_in[0];
    const float* ep = (const float*)d_in[1];
    const float* Wr = (const float*)d_in[2];
    const float* br = (const float*)d_in[3];
    const float* Wn = (const float*)d_in[4];
    const float* bn = (const float*)d_in[5];

    const int T = in_sizes[1] / NEXP;
    float* out_r   = (float*)d_out;
    float* out_idx = (float*)d_out + (size_t)T * NEXP;

    const size_t limb = (size_t)128 * NEMBD * sizeof(f16);     // 512 KB
    const size_t need = 2 * limb + 256 + (size_t)T * sizeof(int);
    if (ws_size >= need) {
        f16* wt_hi = (f16*)d_ws;
        f16* wt_lo = wt_hi + (size_t)128 * NEMBD;
        int* cnt   = (int*)((char*)d_ws + 2 * limb);
        int* list  = (int*)((char*)d_ws + 2 * limb + 256);

        build_wt<<<64, 256, 0, stream>>>(Wr, Wn, wt_hi, wt_lo, cnt);
        router_fused10<<<T / BM, 256, 0, stream>>>(
            x, ep, wt_hi, br, bn, out_r, out_idx, cnt, list);
        router_fixup2<<<T / 64, 512, 0, stream>>>(
            x, ep, wt_hi, wt_lo, br, bn, out_r, out_idx, cnt, list);
    } else {
        router_fused_f32<<<T / 64, 256, 0, stream>>>(
            x, ep, Wr, br, Wn, bn, out_r, out_idx);
    }
}